// Round 5
// baseline (150.728 us; speedup 1.0000x reference)
//
#include <hip/hip_runtime.h>
#include <hip/hip_bf16.h>
#include <math.h>

#define Nn 4096
#define Hdim 256
#define Edim 128
#define Cdim 32
#define Vdim 64
#define Kdim 20
#define G4H 1024
#define OUTS 513

// bucketing workspace (ints)
#define SK 512
#define SC 256
#define RK_OFF 64
#define RC_OFF (RK_OFF + Kdim * SK)      // 10304
#define NLI 18496                         // lstm item count
#define NSI 18497                         // loss item count
#define ITL 18498                         // lstm items (<= 592, cap 640)
#define ITS (ITL + 640)                   // loss items (<= 288, cap 320)
// bucket ints end at 19458 ints = 77832 B

// bf16 W fragment panels: [k][hq][st2(12)][idx(16)][lane(64)] x 16B
#define OFF_WF 81920
#define NWF (Kdim * 4 * 12)               // 960 panels of 16 KB = 15.7 MB

#define LSTM_REGION 592
#define LOSS_REGION 320
#define GRID (LSTM_REGION + LOSS_REGION)  // 912

typedef short bf16x8 __attribute__((ext_vector_type(8)));
typedef float f32x4 __attribute__((ext_vector_type(4)));
typedef unsigned short u16;

__device__ __forceinline__ float sigmoidf_(float x) { return 1.0f / (1.0f + expf(-x)); }

__device__ __forceinline__ bf16x8 cvt8(float4 f0, float4 f1) {
    bf16x8 r;
    __hip_bfloat16 h;
    h = __float2bfloat16(f0.x); r[0] = *(short*)&h;
    h = __float2bfloat16(f0.y); r[1] = *(short*)&h;
    h = __float2bfloat16(f0.z); r[2] = *(short*)&h;
    h = __float2bfloat16(f0.w); r[3] = *(short*)&h;
    h = __float2bfloat16(f1.x); r[4] = *(short*)&h;
    h = __float2bfloat16(f1.y); r[5] = *(short*)&h;
    h = __float2bfloat16(f1.z); r[6] = *(short*)&h;
    h = __float2bfloat16(f1.w); r[7] = *(short*)&h;
    return r;
}

__device__ __forceinline__ void gl_lds16(const void* g, void* l) {
    __builtin_amdgcn_global_load_lds((const __attribute__((address_space(1))) void*)g,
                                     (__attribute__((address_space(3))) void*)l, 16, 0, 0);
}

__device__ __forceinline__ int swz(int r) { return ((r & 3) << 1) | ((r >> 2) & 1); }

// ================= setup A: bucket rows + build compact work lists =================
__global__ __launch_bounds__(1024) void k_bucket(const int* __restrict__ cell_id,
                                                 const int* __restrict__ category,
                                                 int* __restrict__ ws) {
    __shared__ int cnt[32];
    __shared__ int off[33];
    int t = threadIdx.x;
    if (t < 32) cnt[t] = 0;
    __syncthreads();
    int i0 = t * 4;
    if (blockIdx.x == 0) {
        int4 v = ((const int4*)cell_id)[t];
        int r;
        r = atomicAdd(&cnt[v.x], 1); if (r < SK) ws[RK_OFF + v.x * SK + r] = i0 + 0;
        r = atomicAdd(&cnt[v.y], 1); if (r < SK) ws[RK_OFF + v.y * SK + r] = i0 + 1;
        r = atomicAdd(&cnt[v.z], 1); if (r < SK) ws[RK_OFF + v.z * SK + r] = i0 + 2;
        r = atomicAdd(&cnt[v.w], 1); if (r < SK) ws[RK_OFF + v.w * SK + r] = i0 + 3;
        __syncthreads();
        if (t == 0) {
            int a = 0;
            for (int kk = 0; kk < Kdim; kk++) { off[kk] = a; a += (min(cnt[kk], SK) + 31) >> 5; }
            ws[NLI] = a * 4;
        }
        __syncthreads();
        if (t < Kdim) {
            int ns = (min(cnt[t], SK) + 31) >> 5;
            int base = off[t];
            for (int s = 0; s < ns; s++)
                for (int hq = 0; hq < 4; hq++)
                    ws[ITL + (base + s) * 4 + hq] = t | (s << 8) | (hq << 16);
        }
        if (t < 32) ws[t] = min(cnt[t], SK);
    } else {
        int4 v = ((const int4*)category)[t];
        int r;
        r = atomicAdd(&cnt[v.x], 1); if (r < SC) ws[RC_OFF + v.x * SC + r] = i0 + 0;
        r = atomicAdd(&cnt[v.y], 1); if (r < SC) ws[RC_OFF + v.y * SC + r] = i0 + 1;
        r = atomicAdd(&cnt[v.z], 1); if (r < SC) ws[RC_OFF + v.z * SC + r] = i0 + 2;
        r = atomicAdd(&cnt[v.w], 1); if (r < SC) ws[RC_OFF + v.w * SC + r] = i0 + 3;
        __syncthreads();
        if (t == 0) {
            int a = 0;
            for (int cc = 0; cc < Cdim; cc++) { off[cc] = a; a += (min(cnt[cc], SC) + 15) >> 4; }
            ws[NSI] = a;
        }
        __syncthreads();
        if (t < Cdim) {
            int ns = (min(cnt[t], SC) + 15) >> 4;
            int base = off[t];
            for (int s = 0; s < ns; s++)
                ws[ITS + base + s] = t | (s << 8);
        }
        if (t < 32) ws[32 + t] = min(cnt[t], SC);
    }
}

// ================= setup B: W_ih/W_hh -> bf16 fragment panels (pure streaming) =================
// Panel (k,hq,st2): 16 frags idx=g*4+wv; lane l holds W[g*H + hq*64 + wv*16 + (l&15)][st2*32 + (l>>4)*8 ..+8]
// at byte offset panel*16384 + idx*1024 + l*16. (Verified layout, R2 run.)
__global__ __launch_bounds__(256) void k_wconv(
    const float* __restrict__ W_ih, const float* __restrict__ W_hh,
    int* __restrict__ ws)
{
    u16* WF = (u16*)((char*)ws + OFF_WF);
    int b = blockIdx.x, t = threadIdx.x;
    int l = t & 63, sub = t >> 6;
    int c16 = l & 15, qd = l >> 4;

    int k = b / 48; int r = b - k * 48; int hq = r / 12; int st = r - hq * 12;
    int kk = st * 32 + qd * 8;
    #pragma unroll
    for (int rep = 0; rep < 4; rep++) {
        int idx = sub * 4 + rep;               // = g*4 + wv
        int g = idx >> 2, wv = idx & 3;
        int row = g * Hdim + hq * 64 + wv * 16 + c16;
        const float* p = (st < 4)
            ? (W_ih + ((size_t)k * G4H + row) * Edim + kk)
            : (W_hh + ((size_t)k * G4H + row) * Hdim + (kk - Edim));
        float4 lo = *(const float4*)p;
        float4 hi = *(const float4*)(p + 4);
        *(bf16x8*)(WF + ((size_t)(((k * 4 + hq) * 12 + st) * 16 + idx) * 64 + l) * 8) = cvt8(lo, hi);
    }
}

// ================= main: LSTM stages bf16 W panels (BK=64); loss unchanged =================
__global__ __launch_bounds__(256, 4) void k_main(
    const float* __restrict__ vec, const float* __restrict__ inp,
    const float* __restrict__ h_prev, const float* __restrict__ c_prev,
    const float* __restrict__ Wlin, const float* __restrict__ blin,
    const float* __restrict__ Wec, const float* __restrict__ bec,
    const float* __restrict__ Wrel, const float* __restrict__ brel,
    const float* __restrict__ b_ih, const float* __restrict__ b_hh,
    const int* __restrict__ true_idx, const int* __restrict__ ec_idx, const int* __restrict__ rel_idx,
    const int* __restrict__ ws,
    float* __restrict__ out)
{
    __shared__ __align__(16) char smem[40960];   // lstm: Wb 32K bf16 + Xb 8K fp32; loss: 17.7K

    int b = blockIdx.x, t = threadIdx.x;
    int w = t >> 6, l = t & 63;
    int l15 = l & 15, quad = l >> 4;
    int lrow8 = l >> 3, lslot = l & 7;
    int p0 = (quad * 2) ^ swz(l15);

    if (b < LSTM_REGION) {
        // ---- LSTM: 32 rows x 64 hcols (hq quarter) x 4 gates; K = 384, BK = 64 ----
        if (b >= ws[NLI]) return;
        int item = ws[ITL + b];
        int k = item & 255, s = (item >> 8) & 255, hq = item >> 16;
        int cntk = ws[k];
        int rcount = min(32, cntk - s * 32);
        int reg_row = ws[RK_OFF + k * SK + s * 32 + min(l & 31, rcount - 1)];

        char* Wb = smem;                       // 32 KB bf16 frags (2 st2-panels)
        float* Xb = (float*)(smem + 32768);    // 2 x (32 rows x 32 f32) = 8 KB
        const char* WFbase = (const char*)ws + OFF_WF + (size_t)((k * 4 + hq) * 12) * 16384;

        int xr = w * 8 + lrow8;                // X row staged by this lane
        int xrow = __shfl(reg_row, xr);
        int xg = lslot ^ swz(xr);
        const float* xinp = inp + (size_t)xrow * Edim;
        const float* xhp  = h_prev + (size_t)xrow * Hdim;

        // hoisted epilogue operands
        int h = hq * 64 + w * 16 + l15;
        float bs[4];
        #pragma unroll
        for (int g = 0; g < 4; g++)
            bs[g] = b_ih[(size_t)k * G4H + g * Hdim + h] + b_hh[(size_t)k * G4H + g * Hdim + h];
        float cp[2][4];
        #pragma unroll
        for (int m = 0; m < 2; m++)
            #pragma unroll
            for (int reg = 0; reg < 4; reg++) {
                int r = m * 16 + quad * 4 + reg;
                int row = __shfl(reg_row, r);
                cp[m][reg] = c_prev[(size_t)row * Hdim + h];
            }

        f32x4 acc[2][4];
        #pragma unroll
        for (int m = 0; m < 2; m++)
            #pragma unroll
            for (int g = 0; g < 4; g++)
                acc[m][g] = (f32x4){0.f, 0.f, 0.f, 0.f};

        for (int st = 0; st < 6; st++) {
            __syncthreads();
            // W: linear 32 KB panel copy (bf16 frags, already fragment-ordered)
            const char* WFp = WFbase + (size_t)(st * 2) * 16384;
            #pragma unroll
            for (int j = 0; j < 8; j++) {
                int grp = j * 4 + w;
                gl_lds16(WFp + grp * 1024 + l * 16, Wb + grp * 1024);
            }
            // X: two K=32 halves, fp32, per-row slot swizzle
            #pragma unroll
            for (int half = 0; half < 2; half++) {
                int k0 = (st * 2 + half) * 32;
                const float* Xs = (k0 < Edim) ? xinp + k0 : xhp + (k0 - Edim);
                gl_lds16(Xs + xg * 4, Xb + half * 1024 + (w * 8) * 32);
            }
            __syncthreads();

            #pragma unroll
            for (int kk = 0; kk < 2; kk++) {
                bf16x8 af[2], bfr[4];
                #pragma unroll
                for (int m = 0; m < 2; m++) {
                    int row = m * 16 + l15;
                    float4 lo = *(float4*)(Xb + kk * 1024 + row * 32 + p0 * 4);
                    float4 hi = *(float4*)(Xb + kk * 1024 + row * 32 + (p0 ^ 1) * 4);
                    af[m] = cvt8(lo, hi);
                }
                #pragma unroll
                for (int g = 0; g < 4; g++)
                    bfr[g] = *(bf16x8*)(Wb + kk * 16384 + (g * 4 + w) * 1024 + l * 16);
                #pragma unroll
                for (int m = 0; m < 2; m++)
                    #pragma unroll
                    for (int g = 0; g < 4; g++)
                        acc[m][g] = __builtin_amdgcn_mfma_f32_16x16x32_bf16(af[m], bfr[g], acc[m][g], 0, 0, 0);
            }
        }

        #pragma unroll
        for (int m = 0; m < 2; m++) {
            #pragma unroll
            for (int reg = 0; reg < 4; reg++) {
                int r = m * 16 + quad * 4 + reg;
                int row = __shfl(reg_row, r);
                if (r < rcount) {
                    float iv = acc[m][0][reg] + bs[0];
                    float fv = acc[m][1][reg] + bs[1];
                    float gv = acc[m][2][reg] + bs[2];
                    float ov = acc[m][3][reg] + bs[3];
                    float cn = sigmoidf_(fv) * cp[m][reg] + sigmoidf_(iv) * tanhf(gv);
                    float hn = sigmoidf_(ov) * tanhf(cn);
                    out[(size_t)row * OUTS + 1 + h] = hn;
                    out[(size_t)row * OUTS + 1 + Hdim + h] = cn;
                }
            }
        }
    } else {
        // ---- loss: 16 rows x 80 logits; K = 256, BK = 32 (unchanged from R4) ----
        int b2 = b - LSTM_REGION;
        if (b2 >= ws[NSI]) return;
        int item = ws[ITS + b2];
        int c = item & 255, s = item >> 8;
        int cntc = ws[32 + c];
        int rcount = min(16, cntc - s * 16);
        int reg_row = ws[RC_OFF + c * SC + s * 16 + min(l & 15, rcount - 1)];

        float* Wb = (float*)smem;             // 80 rows x 32 f32 (10240 B)
        float* Vb = (float*)(smem + 10240);   // 16 rows x 32 f32 (2048 B)
        float* Lg = (float*)(smem + 12288);   // 16 x 84 f32 (5376 B)

        int xr = (w >= 2) ? ((w - 2) * 8 + lrow8) : 0;
        int xrow = __shfl(reg_row, xr);
        int xg = lslot ^ swz(xr);

        f32x4 a0 = (f32x4){0.f, 0.f, 0.f, 0.f};
        f32x4 a1 = (f32x4){0.f, 0.f, 0.f, 0.f};

        for (int st = 0; st < 8; st++) {
            int ko = st * 32;
            __syncthreads();
            for (int n = w; n < 10; n += 4) {
                int r = n * 8 + lrow8;
                int g = lslot ^ swz(r);
                const float* srcW;
                if (r < 64)      srcW = Wlin + ((size_t)c * Vdim + r) * Hdim;
                else if (r < 66) srcW = Wec + (size_t)(r - 64) * Hdim;
                else if (r < 71) srcW = Wrel + (size_t)(r - 66) * Hdim;
                else             srcW = Wlin + (size_t)c * Vdim * Hdim;
                gl_lds16(srcW + ko + g * 4, Wb + n * 8 * 32);
            }
            if (w >= 2)
                gl_lds16(vec + (size_t)xrow * Hdim + ko + xg * 4, Vb + ((w - 2) * 8) * 32);
            __syncthreads();

            bf16x8 af;
            {
                float4 lo = *(float4*)(Vb + l15 * 32 + p0 * 4);
                float4 hi = *(float4*)(Vb + l15 * 32 + (p0 ^ 1) * 4);
                af = cvt8(lo, hi);
            }
            {
                int row = w * 16 + l15;
                float4 lo = *(float4*)(Wb + row * 32 + p0 * 4);
                float4 hi = *(float4*)(Wb + row * 32 + (p0 ^ 1) * 4);
                bf16x8 b0 = cvt8(lo, hi);
                a0 = __builtin_amdgcn_mfma_f32_16x16x32_bf16(af, b0, a0, 0, 0, 0);
            }
            if (w == 3) {
                int row = 64 + l15;
                float4 lo = *(float4*)(Wb + row * 32 + p0 * 4);
                float4 hi = *(float4*)(Wb + row * 32 + (p0 ^ 1) * 4);
                bf16x8 b1 = cvt8(lo, hi);
                a1 = __builtin_amdgcn_mfma_f32_16x16x32_bf16(af, b1, a1, 0, 0, 0);
            }
        }
        __syncthreads();
        {
            int col = w * 16 + l15;
            float bb = blin[c * Vdim + col];
            #pragma unroll
            for (int reg = 0; reg < 4; reg++)
                Lg[(quad * 4 + reg) * 84 + col] = a0[reg] + bb;
            if (w == 3) {
                int col1 = 64 + l15;
                float bb1 = (l15 < 2) ? bec[l15] : ((l15 < 7) ? brel[l15 - 2] : 0.f);
                #pragma unroll
                for (int reg = 0; reg < 4; reg++)
                    Lg[(quad * 4 + reg) * 84 + col1] = a1[reg] + bb1;
            }
        }
        __syncthreads();
        for (int rr = 0; rr < 4; rr++) {
            int r = w * 4 + rr;
            if (r >= rcount) break;
            int orig = __shfl(reg_row, r);
            float lg = Lg[r * 84 + l];
            float mx = lg;
            for (int ss = 32; ss >= 1; ss >>= 1) mx = fmaxf(mx, __shfl_xor(mx, ss));
            float sm = expf(lg - mx);
            for (int ss = 32; ss >= 1; ss >>= 1) sm += __shfl_xor(sm, ss);
            float lt = __shfl(lg, true_idx[orig]);
            float loss = mx + logf(sm) - lt;
            if (l == 0) {
                float l0 = Lg[r * 84 + 64], l1 = Lg[r * 84 + 65];
                float me2 = fmaxf(l0, l1);
                loss += me2 + logf(expf(l0 - me2) + expf(l1 - me2)) - ((ec_idx[orig] == 0) ? l0 : l1);
                float rl[5] = { Lg[r * 84 + 66], Lg[r * 84 + 67], Lg[r * 84 + 68], Lg[r * 84 + 69], Lg[r * 84 + 70] };
                float mr = rl[0];
                #pragma unroll
                for (int i = 1; i < 5; i++) mr = fmaxf(mr, rl[i]);
                float sr = 0.f;
                #pragma unroll
                for (int i = 0; i < 5; i++) sr += expf(rl[i] - mr);
                loss += mr + logf(sr) - rl[rel_idx[orig]];
                out[(size_t)orig * OUTS] = loss;
            }
        }
    }
}

extern "C" void kernel_launch(void* const* d_in, const int* in_sizes, int n_in,
                              void* d_out, int out_size, void* d_ws, size_t ws_size,
                              hipStream_t stream) {
    const float* vec      = (const float*)d_in[0];
    const float* inp      = (const float*)d_in[1];
    const float* h_prev   = (const float*)d_in[2];
    const float* c_prev   = (const float*)d_in[3];
    const float* Wlin     = (const float*)d_in[4];
    const float* blin     = (const float*)d_in[5];
    const float* Wec      = (const float*)d_in[6];
    const float* bec      = (const float*)d_in[7];
    const float* Wrel     = (const float*)d_in[8];
    const float* brel     = (const float*)d_in[9];
    const float* W_ih     = (const float*)d_in[10];
    const float* b_ih     = (const float*)d_in[11];
    const float* W_hh     = (const float*)d_in[12];
    const float* b_hh     = (const float*)d_in[13];
    const int*   category = (const int*)d_in[14];
    const int*   cell_id  = (const int*)d_in[15];
    const int*   true_idx = (const int*)d_in[16];
    const int*   ec_idx   = (const int*)d_in[17];
    const int*   rel_idx  = (const int*)d_in[18];
    float* out = (float*)d_out;
    int* ws = (int*)d_ws;

    k_bucket<<<2, 1024, 0, stream>>>(cell_id, category, ws);
    k_wconv<<<NWF, 256, 0, stream>>>(W_ih, W_hh, ws);
    k_main<<<GRID, 256, 0, stream>>>(
        vec, inp, h_prev, c_prev, Wlin, blin, Wec, bec, Wrel, brel,
        b_ih, b_hh, true_idx, ec_idx, rel_idx, ws, out);
}

// Round 6
// 148.516 us; speedup vs baseline: 1.0149x; 1.0149x over previous
//
#include <hip/hip_runtime.h>
#include <hip/hip_bf16.h>
#include <math.h>

#define Nn 4096
#define Hdim 256
#define Edim 128
#define Cdim 32
#define Vdim 64
#define Kdim 20
#define G4H 1024
#define OUTS 513

// bucketing workspace (ints)
#define SK 512
#define SC 256
#define RK_OFF 64
#define RC_OFF (RK_OFF + Kdim * SK)      // 10304
#define NLI 18496                         // lstm item count
#define NSI 18497                         // loss item count
#define ITL 18498                         // lstm items (<= 588, cap 640)
#define ITS (ITL + 640)                   // loss items (<= 287, cap 320)

// bf16 W fragment panels (byte offsets in ws)
// LSTM: [k][hq] -> 12 st-panels x 16 KB; panel (k,hq,st): 16 frags idx=g*4+wv,
//   lane l holds W[g*H + hq*64 + wv*16 + (l&15)][st*32 + (l>>4)*8 ..+8]
#define OFF_WF 81920
#define WF_BYTES (Kdim * 4 * 12 * 16384)  // 15,728,640
// loss: panel (c,st): 5 frags wg=0..4, lane l holds row (wg*16+(l&15)) of the
//   80-row logit matrix (64 Wlin | 2 Wec | 5 Wrel | 9 zero), k st*32+(l>>4)*8
#define OFF_LF (OFF_WF + WF_BYTES)
#define LF_BYTES (Cdim * 8 * 5 * 1024)    // 1,310,720

#define NWCONV (Kdim * 4 * 12)            // 960
#define NLCONV (Cdim * 8)                 // 256
#define SETUP_GRID (2 + NWCONV + NLCONV)  // 1218

#define LSTM_REGION 592
#define LOSS_REGION 320
#define GRID (LSTM_REGION + LOSS_REGION)  // 912 = 8 * 114
#define XCHUNK 114

typedef short bf16x8 __attribute__((ext_vector_type(8)));
typedef float f32x4 __attribute__((ext_vector_type(4)));

__device__ __forceinline__ float sigmoidf_(float x) { return 1.0f / (1.0f + expf(-x)); }

__device__ __forceinline__ bf16x8 cvt8(float4 f0, float4 f1) {
    bf16x8 r;
    __hip_bfloat16 h;
    h = __float2bfloat16(f0.x); r[0] = *(short*)&h;
    h = __float2bfloat16(f0.y); r[1] = *(short*)&h;
    h = __float2bfloat16(f0.z); r[2] = *(short*)&h;
    h = __float2bfloat16(f0.w); r[3] = *(short*)&h;
    h = __float2bfloat16(f1.x); r[4] = *(short*)&h;
    h = __float2bfloat16(f1.y); r[5] = *(short*)&h;
    h = __float2bfloat16(f1.z); r[6] = *(short*)&h;
    h = __float2bfloat16(f1.w); r[7] = *(short*)&h;
    return r;
}

__device__ __forceinline__ void gl_lds16(const void* g, void* l) {
    __builtin_amdgcn_global_load_lds((const __attribute__((address_space(1))) void*)g,
                                     (__attribute__((address_space(3))) void*)l, 16, 0, 0);
}

__device__ __forceinline__ int swz(int r) { return ((r & 3) << 1) | ((r >> 2) & 1); }

// ================= setup: bucket (blocks 0,1) + W->bf16 panels (rest), fused =================
__global__ __launch_bounds__(256) void k_setup(
    const int* __restrict__ cell_id, const int* __restrict__ category,
    const float* __restrict__ W_ih, const float* __restrict__ W_hh,
    const float* __restrict__ Wlin, const float* __restrict__ Wec, const float* __restrict__ Wrel,
    int* __restrict__ ws)
{
    int b = blockIdx.x, t = threadIdx.x;

    if (b < 2) {
        // ---- bucketing: 256 threads x 16 ids each ----
        __shared__ int cnt[32];
        __shared__ int off[32];
        if (t < 32) cnt[t] = 0;
        __syncthreads();
        const int* key = (b == 0) ? cell_id : category;
        int cap = (b == 0) ? SK : SC;
        int roff = (b == 0) ? RK_OFF : RC_OFF;
        int stride = cap;
        #pragma unroll
        for (int j = 0; j < 4; j++) {
            int4 v = ((const int4*)key)[t * 4 + j];
            int i0 = t * 16 + j * 4;
            int r;
            r = atomicAdd(&cnt[v.x], 1); if (r < cap) ws[roff + v.x * stride + r] = i0 + 0;
            r = atomicAdd(&cnt[v.y], 1); if (r < cap) ws[roff + v.y * stride + r] = i0 + 1;
            r = atomicAdd(&cnt[v.z], 1); if (r < cap) ws[roff + v.z * stride + r] = i0 + 2;
            r = atomicAdd(&cnt[v.w], 1); if (r < cap) ws[roff + v.w * stride + r] = i0 + 3;
        }
        __syncthreads();
        if (b == 0) {
            if (t == 0) {
                int a = 0;
                for (int kk = 0; kk < Kdim; kk++) { off[kk] = a; a += (min(cnt[kk], SK) + 31) >> 5; }
                ws[NLI] = a * 4;
            }
            __syncthreads();
            if (t < Kdim) {
                int ns = (min(cnt[t], SK) + 31) >> 5;
                int base = off[t] * 4;
                // hq-major: same-(k,hq) items contiguous (panel reuse runs)
                for (int hq = 0; hq < 4; hq++)
                    for (int s = 0; s < ns; s++)
                        ws[ITL + base + hq * ns + s] = t | (s << 8) | (hq << 16);
            }
            if (t < 32) ws[t] = min(cnt[t], SK);
        } else {
            if (t == 0) {
                int a = 0;
                for (int cc = 0; cc < Cdim; cc++) { off[cc] = a; a += (min(cnt[cc], SC) + 15) >> 4; }
                ws[NSI] = a;
            }
            __syncthreads();
            if (t < Cdim) {
                int ns = (min(cnt[t], SC) + 15) >> 4;
                int base = off[t];
                for (int s = 0; s < ns; s++)
                    ws[ITS + base + s] = t | (s << 8);
            }
            if (t < 32) ws[32 + t] = min(cnt[t], SC);
        }
    } else if (b < 2 + NWCONV) {
        // ---- LSTM W -> bf16 fragment panels, nontemporal stores ----
        int b2 = b - 2;
        int l = t & 63, sub = t >> 6;
        int c16 = l & 15, qd = l >> 4;
        int k = b2 / 48; int r = b2 - k * 48; int hq = r / 12; int st = r - hq * 12;
        int kk = st * 32 + qd * 8;
        char* WF = (char*)ws + OFF_WF;
        #pragma unroll
        for (int rep = 0; rep < 4; rep++) {
            int idx = sub * 4 + rep;           // = g*4 + wv
            int g = idx >> 2, wv = idx & 3;
            int row = g * Hdim + hq * 64 + wv * 16 + c16;
            const float* p = (st < 4)
                ? (W_ih + ((size_t)k * G4H + row) * Edim + kk)
                : (W_hh + ((size_t)k * G4H + row) * Hdim + (kk - Edim));
            float4 lo = *(const float4*)p;
            float4 hi = *(const float4*)(p + 4);
            bf16x8 v = cvt8(lo, hi);
            __builtin_nontemporal_store(v,
                (bf16x8*)(WF + (size_t)((((k * 4 + hq) * 12 + st) * 16 + idx) * 64 + l) * 16));
        }
    } else {
        // ---- loss W (Wlin|Wec|Wrel) -> bf16 fragment panels, nontemporal stores ----
        int b3 = b - 2 - NWCONV;
        int l = t & 63, sub = t >> 6;
        int c16 = l & 15, qd = l >> 4;
        int c = b3 >> 3; int st = b3 & 7;
        int kk = st * 32 + qd * 8;
        char* LF = (char*)ws + OFF_LF;
        for (int wg = sub; wg < 5; wg += 4) {
            int lr = wg * 16 + c16;
            bf16x8 v;
            if (lr < 71) {
                const float* p;
                if (lr < 64)      p = Wlin + ((size_t)c * Vdim + lr) * Hdim + kk;
                else if (lr < 66) p = Wec + (size_t)(lr - 64) * Hdim + kk;
                else              p = Wrel + (size_t)(lr - 66) * Hdim + kk;
                float4 lo = *(const float4*)p;
                float4 hi = *(const float4*)(p + 4);
                v = cvt8(lo, hi);
            } else {
                v = (bf16x8){0, 0, 0, 0, 0, 0, 0, 0};
            }
            __builtin_nontemporal_store(v,
                (bf16x8*)(LF + (size_t)(((c * 8 + st) * 5 + wg) * 64 + l) * 16));
        }
    }
}

// ================= main: bf16-panel LDS-DMA + MFMA, XCD-chunked work order =================
__global__ __launch_bounds__(256, 4) void k_main(
    const float* __restrict__ vec, const float* __restrict__ inp,
    const float* __restrict__ h_prev, const float* __restrict__ c_prev,
    const float* __restrict__ blin, const float* __restrict__ bec, const float* __restrict__ brel,
    const float* __restrict__ b_ih, const float* __restrict__ b_hh,
    const int* __restrict__ true_idx, const int* __restrict__ ec_idx, const int* __restrict__ rel_idx,
    const int* __restrict__ ws,
    float* __restrict__ out)
{
    __shared__ __align__(16) char smem[40960];

    int t = threadIdx.x;
    int w = t >> 6, l = t & 63;
    int l15 = l & 15, quad = l >> 4;
    int lrow8 = l >> 3, lslot = l & 7;
    int p0 = (quad * 2) ^ swz(l15);

    // XCD-chunked bijective swizzle: contiguous work ids on one XCD (912 = 8*114)
    int work = (blockIdx.x & 7) * XCHUNK + (blockIdx.x >> 3);

    if (work < LSTM_REGION) {
        // ---- LSTM: 32 rows x 64 hcols (hq) x 4 gates; K=384, BK=64, bf16 W panels ----
        if (work >= ws[NLI]) return;
        int item = ws[ITL + work];
        int k = item & 255, s = (item >> 8) & 255, hq = item >> 16;
        int cntk = ws[k];
        int rcount = min(32, cntk - s * 32);
        int reg_row = ws[RK_OFF + k * SK + s * 32 + min(l & 31, rcount - 1)];

        char* Wb = smem;                       // 32 KB bf16 frags (2 st-panels)
        float* Xb = (float*)(smem + 32768);    // 2 x (32 rows x 32 f32) = 8 KB
        const char* WFbase = (const char*)ws + OFF_WF + (size_t)((k * 4 + hq) * 12) * 16384;

        int xr = w * 8 + lrow8;
        int xrow = __shfl(reg_row, xr);
        int xg = lslot ^ swz(xr);
        const float* xinp = inp + (size_t)xrow * Edim;
        const float* xhp  = h_prev + (size_t)xrow * Hdim;

        // hoisted epilogue operands
        int h = hq * 64 + w * 16 + l15;
        float bs[4];
        #pragma unroll
        for (int g = 0; g < 4; g++)
            bs[g] = b_ih[(size_t)k * G4H + g * Hdim + h] + b_hh[(size_t)k * G4H + g * Hdim + h];
        float cp[2][4];
        #pragma unroll
        for (int m = 0; m < 2; m++)
            #pragma unroll
            for (int reg = 0; reg < 4; reg++) {
                int r = m * 16 + quad * 4 + reg;
                int row = __shfl(reg_row, r);
                cp[m][reg] = c_prev[(size_t)row * Hdim + h];
            }

        f32x4 acc[2][4];
        #pragma unroll
        for (int m = 0; m < 2; m++)
            #pragma unroll
            for (int g = 0; g < 4; g++)
                acc[m][g] = (f32x4){0.f, 0.f, 0.f, 0.f};

        for (int st = 0; st < 6; st++) {
            __syncthreads();
            const char* WFp = WFbase + (size_t)(st * 2) * 16384;
            #pragma unroll
            for (int j = 0; j < 8; j++) {
                int grp = j * 4 + w;
                gl_lds16(WFp + grp * 1024 + l * 16, Wb + grp * 1024);
            }
            #pragma unroll
            for (int half = 0; half < 2; half++) {
                int k0 = (st * 2 + half) * 32;
                const float* Xs = (k0 < Edim) ? xinp + k0 : xhp + (k0 - Edim);
                gl_lds16(Xs + xg * 4, Xb + half * 1024 + (w * 8) * 32);
            }
            __syncthreads();

            #pragma unroll
            for (int kk = 0; kk < 2; kk++) {
                bf16x8 af[2], bfr[4];
                #pragma unroll
                for (int m = 0; m < 2; m++) {
                    int row = m * 16 + l15;
                    float4 lo = *(float4*)(Xb + kk * 1024 + row * 32 + p0 * 4);
                    float4 hi = *(float4*)(Xb + kk * 1024 + row * 32 + (p0 ^ 1) * 4);
                    af[m] = cvt8(lo, hi);
                }
                #pragma unroll
                for (int g = 0; g < 4; g++)
                    bfr[g] = *(bf16x8*)(Wb + kk * 16384 + (g * 4 + w) * 1024 + l * 16);
                #pragma unroll
                for (int m = 0; m < 2; m++)
                    #pragma unroll
                    for (int g = 0; g < 4; g++)
                        acc[m][g] = __builtin_amdgcn_mfma_f32_16x16x32_bf16(af[m], bfr[g], acc[m][g], 0, 0, 0);
            }
        }

        #pragma unroll
        for (int m = 0; m < 2; m++) {
            #pragma unroll
            for (int reg = 0; reg < 4; reg++) {
                int r = m * 16 + quad * 4 + reg;
                int row = __shfl(reg_row, r);
                if (r < rcount) {
                    float iv = acc[m][0][reg] + bs[0];
                    float fv = acc[m][1][reg] + bs[1];
                    float gv = acc[m][2][reg] + bs[2];
                    float ov = acc[m][3][reg] + bs[3];
                    float cn = sigmoidf_(fv) * cp[m][reg] + sigmoidf_(iv) * tanhf(gv);
                    float hn = sigmoidf_(ov) * tanhf(cn);
                    out[(size_t)row * OUTS + 1 + h] = hn;
                    out[(size_t)row * OUTS + 1 + Hdim + h] = cn;
                }
            }
        }
    } else {
        // ---- loss: 16 rows x 80 logits; K=256, BK=32, bf16 W panels ----
        int work2 = work - LSTM_REGION;
        if (work2 >= ws[NSI]) return;
        int item = ws[ITS + work2];
        int c = item & 255, s = item >> 8;
        int cntc = ws[32 + c];
        int rcount = min(16, cntc - s * 16);
        int reg_row = ws[RC_OFF + c * SC + s * 16 + min(l & 15, rcount - 1)];

        char* Wb = smem;                      // 5 KB bf16 frags
        float* Vb = (float*)(smem + 5120);    // 16 rows x 32 f32 (2048 B)
        float* Lg = (float*)(smem + 7168);    // 16 x 84 f32 (5376 B)
        const char* LFbase = (const char*)ws + OFF_LF + (size_t)(c * 8) * 5120;

        int xr = (w >= 2) ? ((w - 2) * 8 + lrow8) : 0;
        int xrow = __shfl(reg_row, xr);
        int xg = lslot ^ swz(xr);

        f32x4 a0 = (f32x4){0.f, 0.f, 0.f, 0.f};
        f32x4 a1 = (f32x4){0.f, 0.f, 0.f, 0.f};

        for (int st = 0; st < 8; st++) {
            __syncthreads();
            const char* LFp = LFbase + (size_t)st * 5120;
            for (int n = w; n < 5; n += 4)
                gl_lds16(LFp + n * 1024 + l * 16, Wb + n * 1024);
            if (w >= 2)
                gl_lds16(vec + (size_t)xrow * Hdim + st * 32 + xg * 4, Vb + ((w - 2) * 8) * 32);
            __syncthreads();

            bf16x8 af;
            {
                float4 lo = *(float4*)(Vb + l15 * 32 + p0 * 4);
                float4 hi = *(float4*)(Vb + l15 * 32 + (p0 ^ 1) * 4);
                af = cvt8(lo, hi);
            }
            {
                bf16x8 b0 = *(bf16x8*)(Wb + w * 1024 + l * 16);
                a0 = __builtin_amdgcn_mfma_f32_16x16x32_bf16(af, b0, a0, 0, 0, 0);
            }
            if (w == 3) {
                bf16x8 b1 = *(bf16x8*)(Wb + 4 * 1024 + l * 16);
                a1 = __builtin_amdgcn_mfma_f32_16x16x32_bf16(af, b1, a1, 0, 0, 0);
            }
        }
        __syncthreads();
        {
            int col = w * 16 + l15;
            float bb = blin[c * Vdim + col];
            #pragma unroll
            for (int reg = 0; reg < 4; reg++)
                Lg[(quad * 4 + reg) * 84 + col] = a0[reg] + bb;
            if (w == 3) {
                int col1 = 64 + l15;
                float bb1 = (l15 < 2) ? bec[l15] : ((l15 < 7) ? brel[l15 - 2] : 0.f);
                #pragma unroll
                for (int reg = 0; reg < 4; reg++)
                    Lg[(quad * 4 + reg) * 84 + col1] = a1[reg] + bb1;
            }
        }
        __syncthreads();
        for (int rr = 0; rr < 4; rr++) {
            int r = w * 4 + rr;
            if (r >= rcount) break;
            int orig = __shfl(reg_row, r);
            float lg = Lg[r * 84 + l];
            float mx = lg;
            for (int ss = 32; ss >= 1; ss >>= 1) mx = fmaxf(mx, __shfl_xor(mx, ss));
            float sm = expf(lg - mx);
            for (int ss = 32; ss >= 1; ss >>= 1) sm += __shfl_xor(sm, ss);
            float lt = __shfl(lg, true_idx[orig]);
            float loss = mx + logf(sm) - lt;
            if (l == 0) {
                float l0 = Lg[r * 84 + 64], l1 = Lg[r * 84 + 65];
                float me2 = fmaxf(l0, l1);
                loss += me2 + logf(expf(l0 - me2) + expf(l1 - me2)) - ((ec_idx[orig] == 0) ? l0 : l1);
                float rl[5] = { Lg[r * 84 + 66], Lg[r * 84 + 67], Lg[r * 84 + 68], Lg[r * 84 + 69], Lg[r * 84 + 70] };
                float mr = rl[0];
                #pragma unroll
                for (int i = 1; i < 5; i++) mr = fmaxf(mr, rl[i]);
                float sr = 0.f;
                #pragma unroll
                for (int i = 0; i < 5; i++) sr += expf(rl[i] - mr);
                loss += mr + logf(sr) - rl[rel_idx[orig]];
                out[(size_t)orig * OUTS] = loss;
            }
        }
    }
}

extern "C" void kernel_launch(void* const* d_in, const int* in_sizes, int n_in,
                              void* d_out, int out_size, void* d_ws, size_t ws_size,
                              hipStream_t stream) {
    const float* vec      = (const float*)d_in[0];
    const float* inp      = (const float*)d_in[1];
    const float* h_prev   = (const float*)d_in[2];
    const float* c_prev   = (const float*)d_in[3];
    const float* Wlin     = (const float*)d_in[4];
    const float* blin     = (const float*)d_in[5];
    const float* Wec      = (const float*)d_in[6];
    const float* bec      = (const float*)d_in[7];
    const float* Wrel     = (const float*)d_in[8];
    const float* brel     = (const float*)d_in[9];
    const float* W_ih     = (const float*)d_in[10];
    const float* b_ih     = (const float*)d_in[11];
    const float* W_hh     = (const float*)d_in[12];
    const float* b_hh     = (const float*)d_in[13];
    const int*   category = (const int*)d_in[14];
    const int*   cell_id  = (const int*)d_in[15];
    const int*   true_idx = (const int*)d_in[16];
    const int*   ec_idx   = (const int*)d_in[17];
    const int*   rel_idx  = (const int*)d_in[18];
    float* out = (float*)d_out;
    int* ws = (int*)d_ws;

    k_setup<<<SETUP_GRID, 256, 0, stream>>>(cell_id, category, W_ih, W_hh,
                                            Wlin, Wec, Wrel, ws);
    k_main<<<GRID, 256, 0, stream>>>(
        vec, inp, h_prev, c_prev, blin, bec, brel,
        b_ih, b_hh, true_idx, ec_idx, rel_idx, ws, out);
}